// Round 4
// baseline (205.506 us; speedup 1.0000x reference)
//
#include <hip/hip_runtime.h>

#define SEQ  20
#define DK   64
#define SSTR 24      // floats per score row (96 B; f4-aligned)
#define WREG 512     // per-wave LDS floats: 480 scores + 20 rinv + pad = 2 KB

// Wave-synchronous LDS fence (each wave owns a private LDS region; lanes run
// in lockstep, so draining lgkmcnt is a sufficient write->read fence).
__device__ __forceinline__ void wave_sync_lds() {
    __builtin_amdgcn_wave_barrier();
    asm volatile("s_waitcnt lgkmcnt(0)" ::: "memory");
    __builtin_amdgcn_wave_barrier();
}

__global__ __launch_bounds__(256, 8)   // pin to 8 waves/EU => <=64 VGPR
void fused_deatt_v4(const float* __restrict__ Qg,
                    const float* __restrict__ Kg,
                    const float* __restrict__ Vg,
                    const float* __restrict__ Mg,
                    float* __restrict__ deAtt,
                    float* __restrict__ attnOut,
                    int nbh)
{
    __shared__ float lds[4 * WREG];   // 8 KB/block -- never the occupancy cap

    const int wv   = threadIdx.x >> 6;
    const int lane = threadIdx.x & 63;
    const int bh   = blockIdx.x * 4 + wv;
    if (bh >= nbh) return;            // wave-uniform; no block barriers below

    float* sS    = lds + wv * WREG;   // [20][SSTR]
    float* sRinv = sS + SEQ * SSTR;   // [20]

    const size_t base = (size_t)bh * (SEQ * DK);
    const float4* gq = reinterpret_cast<const float4*>(Qg + base);
    const float4* gk = reinterpret_cast<const float4*>(Kg + base);
    const float4* gv = reinterpret_cast<const float4*>(Vg + base);
    const float*  m  = Mg + (size_t)bh * (SEQ * SEQ);

    // ---------- Phase B: exp-scores * mask; 4q x 2k tiles, lanes 0..49 ----------
    if (lane < 50) {
        const int qt = lane / 10;          // 0..4  -> q rows 4qt..4qt+3
        const int kt = lane - qt * 10;     // 0..9  -> k cols 2kt, 2kt+1
        const int q0 = qt * 4, k0 = kt * 2;
        float a00 = 0.f, a01 = 0.f, a10 = 0.f, a11 = 0.f;
        float a20 = 0.f, a21 = 0.f, a30 = 0.f, a31 = 0.f;
        #pragma unroll 1                   // TLP over ILP: keep live set < 64
        for (int g = 0; g < 16; ++g) {
            const float4 ka  = gk[(k0    ) * 16 + g];
            const float4 kb  = gk[(k0 + 1) * 16 + g];
            const float4 q0v = gq[(q0 + 0) * 16 + g];
            const float4 q1v = gq[(q0 + 1) * 16 + g];
            const float4 q2v = gq[(q0 + 2) * 16 + g];
            const float4 q3v = gq[(q0 + 3) * 16 + g];
            a00 = fmaf(q0v.x, ka.x, a00); a00 = fmaf(q0v.y, ka.y, a00);
            a00 = fmaf(q0v.z, ka.z, a00); a00 = fmaf(q0v.w, ka.w, a00);
            a01 = fmaf(q0v.x, kb.x, a01); a01 = fmaf(q0v.y, kb.y, a01);
            a01 = fmaf(q0v.z, kb.z, a01); a01 = fmaf(q0v.w, kb.w, a01);
            a10 = fmaf(q1v.x, ka.x, a10); a10 = fmaf(q1v.y, ka.y, a10);
            a10 = fmaf(q1v.z, ka.z, a10); a10 = fmaf(q1v.w, ka.w, a10);
            a11 = fmaf(q1v.x, kb.x, a11); a11 = fmaf(q1v.y, kb.y, a11);
            a11 = fmaf(q1v.z, kb.z, a11); a11 = fmaf(q1v.w, kb.w, a11);
            a20 = fmaf(q2v.x, ka.x, a20); a20 = fmaf(q2v.y, ka.y, a20);
            a20 = fmaf(q2v.z, ka.z, a20); a20 = fmaf(q2v.w, ka.w, a20);
            a21 = fmaf(q2v.x, kb.x, a21); a21 = fmaf(q2v.y, kb.y, a21);
            a21 = fmaf(q2v.z, kb.z, a21); a21 = fmaf(q2v.w, kb.w, a21);
            a30 = fmaf(q3v.x, ka.x, a30); a30 = fmaf(q3v.y, ka.y, a30);
            a30 = fmaf(q3v.z, ka.z, a30); a30 = fmaf(q3v.w, ka.w, a30);
            a31 = fmaf(q3v.x, kb.x, a31); a31 = fmaf(q3v.y, kb.y, a31);
            a31 = fmaf(q3v.z, kb.z, a31); a31 = fmaf(q3v.w, kb.w, a31);
        }
        {
            const float2 mm = *reinterpret_cast<const float2*>(m + (q0 + 0) * SEQ + k0);
            *reinterpret_cast<float2*>(sS + (q0 + 0) * SSTR + k0) =
                make_float2(__expf(a00 * 0.125f) * mm.x, __expf(a01 * 0.125f) * mm.y);
        }
        {
            const float2 mm = *reinterpret_cast<const float2*>(m + (q0 + 1) * SEQ + k0);
            *reinterpret_cast<float2*>(sS + (q0 + 1) * SSTR + k0) =
                make_float2(__expf(a10 * 0.125f) * mm.x, __expf(a11 * 0.125f) * mm.y);
        }
        {
            const float2 mm = *reinterpret_cast<const float2*>(m + (q0 + 2) * SEQ + k0);
            *reinterpret_cast<float2*>(sS + (q0 + 2) * SSTR + k0) =
                make_float2(__expf(a20 * 0.125f) * mm.x, __expf(a21 * 0.125f) * mm.y);
        }
        {
            const float2 mm = *reinterpret_cast<const float2*>(m + (q0 + 3) * SEQ + k0);
            *reinterpret_cast<float2*>(sS + (q0 + 3) * SSTR + k0) =
                make_float2(__expf(a30 * 0.125f) * mm.x, __expf(a31 * 0.125f) * mm.y);
        }
    }
    wave_sync_lds();

    // ---------- Phase C: row sums -> 1/(sum+eps); lanes 0..19 ----------
    if (lane < SEQ) {
        const float4* row = reinterpret_cast<const float4*>(sS + lane * SSTR);
        const float4 r0 = row[0], r1 = row[1], r2 = row[2], r3 = row[3], r4 = row[4];
        const float s = r0.x + r0.y + r0.z + r0.w
                      + r1.x + r1.y + r1.z + r1.w
                      + r2.x + r2.y + r2.z + r2.w
                      + r3.x + r3.y + r3.z + r3.w
                      + r4.x + r4.y + r4.z + r4.w;
        sRinv[lane] = 1.0f / (s + 1e-8f);
    }
    wave_sync_lds();

    // ---------- Phase D: write normalized attn (100 float4 per bh) ----------
    {
        float4* aout = reinterpret_cast<float4*>(attnOut + (size_t)bh * (SEQ * SEQ));
        #pragma unroll
        for (int r = 0; r < 2; ++r) {
            const int idx = lane + r * 64;
            if (idx < 100) {
                const int q  = idx / 5;
                const int g4 = idx - q * 5;
                const float4 s = *reinterpret_cast<const float4*>(sS + q * SSTR + g4 * 4);
                const float rv = sRinv[q];
                aout[idx] = make_float4(s.x * rv, s.y * rv, s.z * rv, s.w * rv);
            }
        }
    }

    // ---------- Phase E: deAtt = (attn + Md) @ V; 64 lanes (qp, dg) ----------
    {
        const int qp = lane >> 4;        // 0..3 -> q rows qp*5 .. qp*5+4
        const int dg = lane & 15;        // output float4 column group
        float rv[5];
        #pragma unroll
        for (int j = 0; j < 5; ++j) rv[j] = sRinv[qp * 5 + j];

        float4 acc[5];
        #pragma unroll
        for (int j = 0; j < 5; ++j) acc[j] = make_float4(0.f, 0.f, 0.f, 0.f);

        #pragma unroll 1                 // keep only one k-quad's V live
        for (int k4 = 0; k4 < 5; ++k4) {
            const int kb = k4 * 4;
            const float4 v0 = gv[(kb + 0) * 16 + dg];   // 16 distinct f4 = 256 B
            const float4 v1 = gv[(kb + 1) * 16 + dg];   // per instr: coalesced
            const float4 v2 = gv[(kb + 2) * 16 + dg];
            const float4 v3 = gv[(kb + 3) * 16 + dg];
            const float kf0 = (float)(kb + 0), kf1 = (float)(kb + 1);
            const float kf2 = (float)(kb + 2), kf3 = (float)(kb + 3);
            #pragma unroll
            for (int j = 0; j < 5; ++j) {
                const int q = qp * 5 + j;
                const float qf = (float)q;
                const float4 s = *reinterpret_cast<const float4*>(sS + q * SSTR + kb);
                const float w0 = fmaf(s.x, rv[j], -fabsf(qf - kf0));
                const float w1 = fmaf(s.y, rv[j], -fabsf(qf - kf1));
                const float w2 = fmaf(s.z, rv[j], -fabsf(qf - kf2));
                const float w3 = fmaf(s.w, rv[j], -fabsf(qf - kf3));
                acc[j].x = fmaf(w0, v0.x, acc[j].x); acc[j].x = fmaf(w1, v1.x, acc[j].x);
                acc[j].x = fmaf(w2, v2.x, acc[j].x); acc[j].x = fmaf(w3, v3.x, acc[j].x);
                acc[j].y = fmaf(w0, v0.y, acc[j].y); acc[j].y = fmaf(w1, v1.y, acc[j].y);
                acc[j].y = fmaf(w2, v2.y, acc[j].y); acc[j].y = fmaf(w3, v3.y, acc[j].y);
                acc[j].z = fmaf(w0, v0.z, acc[j].z); acc[j].z = fmaf(w1, v1.z, acc[j].z);
                acc[j].z = fmaf(w2, v2.z, acc[j].z); acc[j].z = fmaf(w3, v3.z, acc[j].z);
                acc[j].w = fmaf(w0, v0.w, acc[j].w); acc[j].w = fmaf(w1, v1.w, acc[j].w);
                acc[j].w = fmaf(w2, v2.w, acc[j].w); acc[j].w = fmaf(w3, v3.w, acc[j].w);
            }
        }
        #pragma unroll
        for (int j = 0; j < 5; ++j) {
            const int q = qp * 5 + j;
            reinterpret_cast<float4*>(deAtt + base + q * DK)[dg] = acc[j];
        }
    }
}

extern "C" void kernel_launch(void* const* d_in, const int* in_sizes, int n_in,
                              void* d_out, int out_size, void* d_ws, size_t ws_size,
                              hipStream_t stream) {
    const float* Q = (const float*)d_in[0];
    const float* K = (const float*)d_in[1];
    const float* V = (const float*)d_in[2];
    const float* M = (const float*)d_in[3];
    float* out = (float*)d_out;

    const int nbh = in_sizes[0] / (SEQ * DK);        // B*H = 8192
    float* deAtt = out;                              // [nbh, SEQ, DK]
    float* attn  = out + (size_t)nbh * SEQ * DK;     // [nbh, SEQ, SEQ]

    const int blocks = (nbh + 3) / 4;
    fused_deatt_v4<<<blocks, 256, 0, stream>>>(Q, K, V, M, deAtt, attn, nbh);
}